// Round 4
// baseline (661.512 us; speedup 1.0000x reference)
//
#include <hip/hip_runtime.h>

#define LOG2E 1.4426950408889634f
#define BN_EPS 1e-5f

typedef float f32x2 __attribute__((ext_vector_type(2)));
typedef float f32x4 __attribute__((ext_vector_type(4)));

__device__ __forceinline__ float sigf(float x){
    return __builtin_amdgcn_rcpf(1.f + __builtin_amdgcn_exp2f(-LOG2E * x));
}
// sig(a)*tanh(b) with a single rcp
__device__ __forceinline__ float sigtanh(float a, float b){
    float A  = __builtin_amdgcn_exp2f(LOG2E * a);
    float Bv = __builtin_amdgcn_exp2f((2.f * LOG2E) * b);
    float num = A * (Bv - 1.f);
    float den = (1.f + A) * (1.f + Bv);
    return num * __builtin_amdgcn_rcpf(den);
}
__device__ __forceinline__ float relu_(float x){ return fmaxf(x, 0.f); }

__device__ __forceinline__ float wsum(float v){
    #pragma unroll
    for (int m = 32; m >= 1; m >>= 1) v += __shfl_xor(v, m, 64);
    return v;
}

__device__ constexpr int TRI(int j, int l){ return j*9 - j*(j-1)/2 + (l - j); }

__device__ __forceinline__ float ld_stat(const float* p){
    return __hip_atomic_load(p, __ATOMIC_RELAXED, __HIP_MEMORY_SCOPE_AGENT);
}

__device__ __forceinline__ void load_h0(const float* __restrict__ x, const float* __restrict__ emb,
                                        long row, float h0[9])
{
    const float4* xv = (const float4*)(x + row * 8);
    float4 p = xv[0];
    float4 q = xv[1];
    int idx = (int)p.x;
    float2 e = ((const float2*)emb)[idx];
    h0[0] = e.x; h0[1] = e.y;
    h0[2] = p.y; h0[3] = p.z; h0[4] = p.w;
    h0[5] = q.x; h0[6] = q.y; h0[7] = q.z; h0[8] = q.w;
}

// BN1 scale/shift from h0 moments (atomic-load reads); threads 0..17 -> LDS
__device__ __forceinline__ void bn1_from_moments(const float* __restrict__ stats,
                                                 const float* __restrict__ W1, const float* __restrict__ b1,
                                                 const float* __restrict__ g1, const float* __restrict__ be1,
                                                 float invB, float* smem_sc, float* smem_sh)
{
    if (threadIdx.x < 18){
        int k = threadIdx.x;
        float w[9];
        #pragma unroll
        for (int j = 0; j < 9; ++j) w[j] = W1[k*9 + j];
        float dot9 = 0.f, q = 0.f;
        #pragma unroll
        for (int j = 0; j < 9; ++j){
            float s1 = ld_stat(&stats[j]);
            dot9 = fmaf(w[j], s1, dot9);
            q = fmaf(w[j]*w[j], ld_stat(&stats[16 + TRI(j,j)]), q);
            #pragma unroll
            for (int l = j+1; l < 9; ++l)
                q = fmaf(2.f*w[j]*w[l], ld_stat(&stats[16 + TRI(j,l)]), q);
        }
        float m1  = dot9 * invB;
        float var = fmaf(-m1, m1, q * invB);
        float mu  = m1 + b1[k];
        float sc  = g1[k] * __builtin_amdgcn_rsqf(var + BN_EPS);
        smem_sc[k] = sc;
        smem_sh[k] = fmaf(-mu, sc, be1[k]);
    }
    __syncthreads();
}

__device__ __forceinline__ f32x2 mk2(float a, float b){ f32x2 r; r.x=a; r.y=b; return r; }
__device__ __forceinline__ f32x4 mk4(float a, float b, float c, float d){ f32x4 r; r.x=a; r.y=b; r.z=c; r.w=d; return r; }

struct KParams {
    const float *x, *emb, *W1, *b1, *g1, *be1, *W2, *b2, *g2, *be2;
    const float *w1f, *u1f, *c1f, *w1r, *u1r, *c1r;
    const float *w2f, *u2f, *c2f, *w2r, *u2r, *c2r;
    float* stats;
    float* out;
    int B;
    int nb;
};

// manual grid barrier: all nb blocks co-resident (guaranteed by launch_bounds + grid size)
__device__ __forceinline__ void gridbar(int* ctr, int nb){
    __syncthreads();
    if (threadIdx.x == 0){
        __threadfence();
        atomicAdd(ctr, 1);
        while (__hip_atomic_load(ctr, __ATOMIC_ACQUIRE, __HIP_MEMORY_SCOPE_AGENT) < nb)
            __builtin_amdgcn_s_sleep(8);
    }
    __syncthreads();
}

// ============ fused persistent kernel (normal launch, graph-capturable) ============
__global__ __launch_bounds__(256, 4) void k_fused2(KParams p)
{
    const int tid = threadIdx.x;
    const long base = (long)blockIdx.x * 1024 + tid;
    const float invB = 1.f / (float)p.B;
    const bool l0 = (tid & 63) == 0;
    int* bar = (int*)(p.stats + 120);

    // ---------------- P1: h0 moments ----------------
    {
        float s9[9], mt[45];
        #pragma unroll
        for (int j = 0; j < 9; ++j) s9[j] = 0.f;
        #pragma unroll
        for (int t = 0; t < 45; ++t) mt[t] = 0.f;

        #pragma unroll
        for (int r = 0; r < 4; ++r){
            long row = base + r * 256;
            if (row < p.B){
                float h0[9];
                load_h0(p.x, p.emb, row, h0);
                #pragma unroll
                for (int j = 0; j < 9; ++j){
                    s9[j] += h0[j];
                    #pragma unroll
                    for (int l = j; l < 9; ++l)
                        mt[TRI(j,l)] = fmaf(h0[j], h0[l], mt[TRI(j,l)]);
                }
            }
        }
        __shared__ float sm[54];
        if (tid < 54) sm[tid] = 0.f;
        __syncthreads();
        #pragma unroll
        for (int j = 0; j < 9; ++j){
            float v = wsum(s9[j]);
            if (l0) atomicAdd(&sm[j], v);
        }
        #pragma unroll
        for (int t = 0; t < 45; ++t){
            float v = wsum(mt[t]);
            if (l0) atomicAdd(&sm[9 + t], v);
        }
        __syncthreads();
        if (tid < 9)       atomicAdd(&p.stats[tid], sm[tid]);
        else if (tid < 54) atomicAdd(&p.stats[16 + tid - 9], sm[tid]);
    }

    gridbar(bar, p.nb);

    // ---------------- P2: BN1 -> a1 -> z2 (regs) + z2 stats ----------------
    float z2r[4][9];
    {
        __shared__ float s_sc[18], s_sh[18];
        bn1_from_moments(p.stats, p.W1, p.b1, p.g1, p.be1, invB, s_sc, s_sh);

        float as[9], aq[9];
        #pragma unroll
        for (int k = 0; k < 9; ++k){ as[k] = 0.f; aq[k] = 0.f; }

        #pragma unroll
        for (int r = 0; r < 4; ++r){
            long row = base + r * 256;
            if (row < p.B){
                float h0[9];
                load_h0(p.x, p.emb, row, h0);
                float a1[18];
                #pragma unroll
                for (int k = 0; k < 18; ++k){
                    float s = p.b1[k];
                    #pragma unroll
                    for (int j = 0; j < 9; ++j) s = fmaf(p.W1[k*9 + j], h0[j], s);
                    a1[k] = relu_(fmaf(s_sc[k], s, s_sh[k]));
                }
                #pragma unroll
                for (int k = 0; k < 9; ++k){
                    float s = p.b2[k];
                    #pragma unroll
                    for (int j = 0; j < 18; ++j) s = fmaf(p.W2[k*18 + j], a1[j], s);
                    z2r[r][k] = s;
                    as[k] += s; aq[k] = fmaf(s, s, aq[k]);
                }
            } else {
                #pragma unroll
                for (int k = 0; k < 9; ++k) z2r[r][k] = 0.f;
            }
        }
        __shared__ float sm2[18];
        if (tid < 18) sm2[tid] = 0.f;
        __syncthreads();
        #pragma unroll
        for (int k = 0; k < 9; ++k){
            float s = wsum(as[k]);
            float q = wsum(aq[k]);
            if (l0){ atomicAdd(&sm2[k], s); atomicAdd(&sm2[9 + k], q); }
        }
        __syncthreads();
        if (tid < 9)       atomicAdd(&p.stats[64 + tid], sm2[tid]);
        else if (tid < 18) atomicAdd(&p.stats[80 + tid - 9], sm2[tid]);
    }

    gridbar(bar + 1, p.nb);

    // ---------------- P3: BN2 + biLSTM x2 + output ----------------
    __shared__ float s_sc2[9], s_sh2[9];
    if (tid < 9){
        int k = tid;
        float mu  = ld_stat(&p.stats[64 + k]) * invB;
        float var = fmaf(-mu, mu, ld_stat(&p.stats[80 + k]) * invB);
        float sc  = p.g2[k] * __builtin_amdgcn_rsqf(var + BN_EPS);
        s_sc2[k] = sc;
        s_sh2[k] = fmaf(-mu, sc, p.be2[k]);
    }
    __syncthreads();
    float sc2[9], sh2[9];
    #pragma unroll
    for (int k = 0; k < 9; ++k){ sc2[k] = s_sc2[k]; sh2[k] = s_sh2[k]; }

    // LSTM1 weights packed [fwd0, fwd1, rev0, rev1]
    f32x4 W4[4], U04[4], U14[4], B4[4];
    #pragma unroll
    for (int g = 0; g < 4; ++g){
        W4[g]  = mk4(p.w1f[2*g], p.w1f[2*g+1], p.w1r[2*g], p.w1r[2*g+1]);
        U04[g] = mk4(p.u1f[(2*g)*2], p.u1f[(2*g+1)*2], p.u1r[(2*g)*2], p.u1r[(2*g+1)*2]);
        U14[g] = mk4(p.u1f[(2*g)*2+1], p.u1f[(2*g+1)*2+1], p.u1r[(2*g)*2+1], p.u1r[(2*g+1)*2+1]);
        B4[g]  = mk4(p.c1f[2*g], p.c1f[2*g+1], p.c1r[2*g], p.c1r[2*g+1]);
    }
    // LSTM2 weights packed [fwd, rev]
    f32x2 w2v[4][4], u2v[4], b2v[4];
    #pragma unroll
    for (int r = 0; r < 4; ++r){
        #pragma unroll
        for (int j = 0; j < 4; ++j) w2v[r][j] = mk2(p.w2f[4*r + j], p.w2r[4*r + j]);
        u2v[r] = mk2(p.u2f[r], p.u2r[r]);
        b2v[r] = mk2(p.c2f[r], p.c2r[r]);
    }

    #pragma unroll
    for (int r = 0; r < 4; ++r){
        long row = base + r * 256;
        if (row >= p.B) continue;

        float a2[9];
        #pragma unroll
        for (int k = 0; k < 9; ++k)
            a2[k] = relu_(fmaf(sc2[k], z2r[r][k], sh2[k]));

        // biLSTM layer 1
        f32x4 h4 = {0.f, 0.f, 0.f, 0.f};
        f32x4 c4 = {0.f, 0.f, 0.f, 0.f};
        float u_[9][4];
        #pragma unroll
        for (int s = 0; s < 9; ++s){
            const int tf = s, tr = 8 - s;
            f32x4 xt4 = mk4(a2[tf], a2[tf], a2[tr], a2[tr]);
            f32x4 hx  = mk4(h4.x, h4.x, h4.z, h4.z);
            f32x4 hy  = mk4(h4.y, h4.y, h4.w, h4.w);
            f32x4 z[4];
            #pragma unroll
            for (int g = 0; g < 4; ++g)
                z[g] = __builtin_elementwise_fma(W4[g], xt4,
                        __builtin_elementwise_fma(U04[g], hx,
                         __builtin_elementwise_fma(U14[g], hy, B4[g])));
            // fused i,g,f with one rcp: icg = A(Bv-1)(1+F)/P, fs = F(1+A)(1+Bv)/P
            #pragma unroll
            for (int c = 0; c < 4; ++c){
                float A  = __builtin_amdgcn_exp2f(LOG2E * z[0][c]);
                float Bv = __builtin_amdgcn_exp2f((2.f*LOG2E) * z[2][c]);
                float F  = __builtin_amdgcn_exp2f(LOG2E * z[1][c]);
                float den2 = (1.f + A) * (1.f + Bv);
                float rp = __builtin_amdgcn_rcpf(den2 * (1.f + F));
                float icg = A * (Bv - 1.f) * (1.f + F) * rp;
                float fs  = F * den2 * rp;
                c4[c] = fmaf(fs, c4[c], icg);
                h4[c] = sigtanh(z[3][c], c4[c]);
            }
            u_[tf][0] = relu_(h4.x);
            u_[tf][1] = relu_(h4.y);
            u_[tr][2] = relu_(h4.z);
            u_[tr][3] = relu_(h4.w);
        }

        // biLSTM layer 2
        f32x2 h2 = {0.f, 0.f};
        f32x2 cc = {0.f, 0.f};
        float of[9], orr[9];
        #pragma unroll
        for (int s = 0; s < 9; ++s){
            const int tf = s, tr = 8 - s;
            f32x2 z[4];
            #pragma unroll
            for (int g = 0; g < 4; ++g){
                f32x2 acc = __builtin_elementwise_fma(u2v[g], h2, b2v[g]);
                #pragma unroll
                for (int j = 0; j < 4; ++j)
                    acc = __builtin_elementwise_fma(w2v[g][j], mk2(u_[tf][j], u_[tr][j]), acc);
                z[g] = acc;
            }
            #pragma unroll
            for (int c = 0; c < 2; ++c){
                float A  = __builtin_amdgcn_exp2f(LOG2E * z[0][c]);
                float Bv = __builtin_amdgcn_exp2f((2.f*LOG2E) * z[2][c]);
                float F  = __builtin_amdgcn_exp2f(LOG2E * z[1][c]);
                float den2 = (1.f + A) * (1.f + Bv);
                float rp = __builtin_amdgcn_rcpf(den2 * (1.f + F));
                float icg = A * (Bv - 1.f) * (1.f + F) * rp;
                float fs  = F * den2 * rp;
                cc[c] = fmaf(fs, cc[c], icg);
            }
            float hfo = sigtanh(z[3][0], cc.x);
            float hro = sigtanh(z[3][1], cc.y);
            h2 = mk2(hfo, hro);
            of[tf]  = hfo;
            orr[tr] = hro;
        }
        float2* op = (float2*)(p.out + row * 18);
        #pragma unroll
        for (int t = 0; t < 9; ++t) op[t] = make_float2(of[t], orr[t]);
    }
}

// ============================ fallback 3-kernel path (round-2 proven) ============================
__global__ __launch_bounds__(256) void k_moments(const float* __restrict__ x, const float* __restrict__ emb,
                                                 float* __restrict__ stats, int B)
{
    float s9[9], mt[45];
    #pragma unroll
    for (int j = 0; j < 9; ++j) s9[j] = 0.f;
    #pragma unroll
    for (int t = 0; t < 45; ++t) mt[t] = 0.f;

    long base = (long)blockIdx.x * 1024 + threadIdx.x;
    #pragma unroll
    for (int r = 0; r < 4; ++r){
        long row = base + r * 256;
        if (row < B){
            float h0[9];
            load_h0(x, emb, row, h0);
            #pragma unroll
            for (int j = 0; j < 9; ++j){
                s9[j] += h0[j];
                #pragma unroll
                for (int l = j; l < 9; ++l)
                    mt[TRI(j,l)] = fmaf(h0[j], h0[l], mt[TRI(j,l)]);
            }
        }
    }
    __shared__ float sm[54];
    if (threadIdx.x < 54) sm[threadIdx.x] = 0.f;
    __syncthreads();
    bool l0 = (threadIdx.x & 63) == 0;
    #pragma unroll
    for (int j = 0; j < 9; ++j){
        float v = wsum(s9[j]);
        if (l0) atomicAdd(&sm[j], v);
    }
    #pragma unroll
    for (int t = 0; t < 45; ++t){
        float v = wsum(mt[t]);
        if (l0) atomicAdd(&sm[9 + t], v);
    }
    __syncthreads();
    if (threadIdx.x < 9)  atomicAdd(&stats[threadIdx.x], sm[threadIdx.x]);
    else if (threadIdx.x < 54) atomicAdd(&stats[16 + threadIdx.x - 9], sm[threadIdx.x]);
}

__global__ __launch_bounds__(256) void k_stats2(KParams p)
{
    __shared__ float s_sc[18], s_sh[18];
    bn1_from_moments(p.stats, p.W1, p.b1, p.g1, p.be1, 1.f/(float)p.B, s_sc, s_sh);

    float as[9], aq[9];
    #pragma unroll
    for (int k = 0; k < 9; ++k){ as[k] = 0.f; aq[k] = 0.f; }

    long base = (long)blockIdx.x * 1024 + threadIdx.x;
    #pragma unroll
    for (int r = 0; r < 4; ++r){
        long row = base + r * 256;
        if (row < p.B){
            float h0[9];
            load_h0(p.x, p.emb, row, h0);
            float a1[18];
            #pragma unroll
            for (int k = 0; k < 18; ++k){
                float s = p.b1[k];
                #pragma unroll
                for (int j = 0; j < 9; ++j) s = fmaf(p.W1[k*9 + j], h0[j], s);
                a1[k] = relu_(fmaf(s_sc[k], s, s_sh[k]));
            }
            #pragma unroll
            for (int k = 0; k < 9; ++k){
                float s = p.b2[k];
                #pragma unroll
                for (int j = 0; j < 18; ++j) s = fmaf(p.W2[k*18 + j], a1[j], s);
                as[k] += s; aq[k] = fmaf(s, s, aq[k]);
            }
        }
    }
    __shared__ float sm[18];
    if (threadIdx.x < 18) sm[threadIdx.x] = 0.f;
    __syncthreads();
    bool l0 = (threadIdx.x & 63) == 0;
    #pragma unroll
    for (int k = 0; k < 9; ++k){
        float s = wsum(as[k]);
        float q = wsum(aq[k]);
        if (l0){ atomicAdd(&sm[k], s); atomicAdd(&sm[9 + k], q); }
    }
    __syncthreads();
    if (threadIdx.x < 9)       atomicAdd(&p.stats[64 + threadIdx.x], sm[threadIdx.x]);
    else if (threadIdx.x < 18) atomicAdd(&p.stats[80 + threadIdx.x - 9], sm[threadIdx.x]);
}

__global__ __launch_bounds__(256) void k_main_fb(KParams p)
{
    __shared__ float s_sc[18], s_sh[18];
    float invB = 1.f / (float)p.B;
    bn1_from_moments(p.stats, p.W1, p.b1, p.g1, p.be1, invB, s_sc, s_sh);

    long row = (long)blockIdx.x * 256 + threadIdx.x;
    if (row >= p.B) return;

    float h0[9];
    load_h0(p.x, p.emb, row, h0);
    float a1[18];
    #pragma unroll
    for (int k = 0; k < 18; ++k){
        float s = p.b1[k];
        #pragma unroll
        for (int j = 0; j < 9; ++j) s = fmaf(p.W1[k*9 + j], h0[j], s);
        a1[k] = relu_(fmaf(s_sc[k], s, s_sh[k]));
    }
    float a2[9];
    #pragma unroll
    for (int k = 0; k < 9; ++k){
        float s = p.b2[k];
        #pragma unroll
        for (int j = 0; j < 18; ++j) s = fmaf(p.W2[k*18 + j], a1[j], s);
        float mu  = ld_stat(&p.stats[64 + k]) * invB;
        float var = fmaf(-mu, mu, ld_stat(&p.stats[80 + k]) * invB);
        float sc  = p.g2[k] * __builtin_amdgcn_rsqf(var + BN_EPS);
        a2[k] = relu_(fmaf(sc, s - mu, p.be2[k]));
    }

    f32x4 W4[4], U04[4], U14[4], B4[4];
    #pragma unroll
    for (int g = 0; g < 4; ++g){
        W4[g]  = mk4(p.w1f[2*g], p.w1f[2*g+1], p.w1r[2*g], p.w1r[2*g+1]);
        U04[g] = mk4(p.u1f[(2*g)*2], p.u1f[(2*g+1)*2], p.u1r[(2*g)*2], p.u1r[(2*g+1)*2]);
        U14[g] = mk4(p.u1f[(2*g)*2+1], p.u1f[(2*g+1)*2+1], p.u1r[(2*g)*2+1], p.u1r[(2*g+1)*2+1]);
        B4[g]  = mk4(p.c1f[2*g], p.c1f[2*g+1], p.c1r[2*g], p.c1r[2*g+1]);
    }
    f32x4 h4 = {0.f, 0.f, 0.f, 0.f};
    f32x4 c4 = {0.f, 0.f, 0.f, 0.f};
    float u_[9][4];
    #pragma unroll
    for (int s = 0; s < 9; ++s){
        const int tf = s, tr = 8 - s;
        f32x4 xt4 = mk4(a2[tf], a2[tf], a2[tr], a2[tr]);
        f32x4 hx  = mk4(h4.x, h4.x, h4.z, h4.z);
        f32x4 hy  = mk4(h4.y, h4.y, h4.w, h4.w);
        f32x4 z[4];
        #pragma unroll
        for (int g = 0; g < 4; ++g)
            z[g] = __builtin_elementwise_fma(W4[g], xt4,
                    __builtin_elementwise_fma(U04[g], hx,
                     __builtin_elementwise_fma(U14[g], hy, B4[g])));
        #pragma unroll
        for (int c = 0; c < 4; ++c){
            float icg = sigtanh(z[0][c], z[2][c]);
            float fs  = sigf(z[1][c]);
            c4[c] = fmaf(fs, c4[c], icg);
            h4[c] = sigtanh(z[3][c], c4[c]);
        }
        u_[tf][0] = relu_(h4.x);
        u_[tf][1] = relu_(h4.y);
        u_[tr][2] = relu_(h4.z);
        u_[tr][3] = relu_(h4.w);
    }

    f32x2 w2v[4][4], u2v[4], b2v[4];
    #pragma unroll
    for (int r = 0; r < 4; ++r){
        #pragma unroll
        for (int j = 0; j < 4; ++j) w2v[r][j] = mk2(p.w2f[4*r + j], p.w2r[4*r + j]);
        u2v[r] = mk2(p.u2f[r], p.u2r[r]);
        b2v[r] = mk2(p.c2f[r], p.c2r[r]);
    }
    f32x2 h2 = {0.f, 0.f};
    f32x2 cc = {0.f, 0.f};
    float of[9], orr[9];
    #pragma unroll
    for (int s = 0; s < 9; ++s){
        const int tf = s, tr = 8 - s;
        f32x2 z[4];
        #pragma unroll
        for (int g = 0; g < 4; ++g){
            f32x2 acc = __builtin_elementwise_fma(u2v[g], h2, b2v[g]);
            #pragma unroll
            for (int j = 0; j < 4; ++j)
                acc = __builtin_elementwise_fma(w2v[g][j], mk2(u_[tf][j], u_[tr][j]), acc);
            z[g] = acc;
        }
        #pragma unroll
        for (int c = 0; c < 2; ++c){
            float icg = sigtanh(z[0][c], z[2][c]);
            float fs  = sigf(z[1][c]);
            cc[c] = fmaf(fs, cc[c], icg);
        }
        float hfo = sigtanh(z[3][0], cc.x);
        float hro = sigtanh(z[3][1], cc.y);
        h2 = mk2(hfo, hro);
        of[tf]  = hfo;
        orr[tr] = hro;
    }
    float2* op = (float2*)(p.out + row * 18);
    #pragma unroll
    for (int t = 0; t < 9; ++t) op[t] = make_float2(of[t], orr[t]);
}

extern "C" void kernel_launch(void* const* d_in, const int* in_sizes, int n_in,
                              void* d_out, int out_size, void* d_ws, size_t ws_size,
                              hipStream_t stream)
{
    KParams p;
    p.x    = (const float*)d_in[0];
    p.emb  = (const float*)d_in[1];
    p.W1   = (const float*)d_in[2];
    p.b1   = (const float*)d_in[3];
    p.g1   = (const float*)d_in[4];
    p.be1  = (const float*)d_in[5];
    p.W2   = (const float*)d_in[6];
    p.b2   = (const float*)d_in[7];
    p.g2   = (const float*)d_in[8];
    p.be2  = (const float*)d_in[9];
    p.w1f  = (const float*)d_in[10];
    p.u1f  = (const float*)d_in[11];
    p.c1f  = (const float*)d_in[12];
    p.w1r  = (const float*)d_in[13];
    p.u1r  = (const float*)d_in[14];
    p.c1r  = (const float*)d_in[15];
    p.w2f  = (const float*)d_in[16];
    p.u2f  = (const float*)d_in[17];
    p.c2f  = (const float*)d_in[18];
    p.w2r  = (const float*)d_in[19];
    p.u2r  = (const float*)d_in[20];
    p.c2r  = (const float*)d_in[21];
    p.stats = (float*)d_ws;
    p.out   = (float*)d_out;
    p.B     = in_sizes[0] / 8;
    p.nb    = 1024;

    // stats layout: [0:9] sum h0, [16:61] tri moments, [64:73] sum z2,
    // [80:89] sumsq z2, [120],[121] barrier counters
    hipMemsetAsync(d_ws, 0, 512, stream);

    // fused path requires every row covered by the fixed 1024x256x4 layout
    if (p.B <= 1024 * 256 * 4){
        k_fused2<<<1024, 256, 0, stream>>>(p);
    } else {
        int nb  = (p.B + 1023) / 1024;
        int nb3 = (p.B + 255) / 256;
        k_moments<<<nb, 256, 0, stream>>>(p.x, p.emb, p.stats, p.B);
        k_stats2<<<nb, 256, 0, stream>>>(p);
        k_main_fb<<<nb3, 256, 0, stream>>>(p);
    }
}

// Round 5
// 265.108 us; speedup vs baseline: 2.4953x; 2.4953x over previous
//
#include <hip/hip_runtime.h>

#define LOG2E 1.4426950408889634f
#define BN_EPS 1e-5f

// ws float offsets
#define WS_BAR   120   // barrier counter (int)
#define WS_L1    128   // per dir (stride 32): w[8], u[16], b[8]  (pre-scaled)
#define WS_L2    192   // per dir (stride 24): W[16], U[4], b[4]  (pre-scaled)
#define WS_BN2S  240   // sc2[9]
#define WS_BN2H  249   // sh2[9]
#define WS_BN1S  258   // sc1[18]
#define WS_BN1H  276   // sh1[18]
#define WS_Z2    1024  // z2 cache, col-major [9][B]

__device__ __forceinline__ float relu_(float x){ return fmaxf(x, 0.f); }

__device__ __forceinline__ float wsum(float v){
    #pragma unroll
    for (int m = 32; m >= 1; m >>= 1) v += __shfl_xor(v, m, 64);
    return v;
}

__device__ constexpr int TRI(int j, int l){ return j*9 - j*(j-1)/2 + (l - j); }

__device__ __forceinline__ float ld_stat(const float* p){
    return __hip_atomic_load(p, __ATOMIC_RELAXED, __HIP_MEMORY_SCOPE_AGENT);
}

__device__ __forceinline__ void load_h0(const float* __restrict__ x, const float* __restrict__ emb,
                                        long row, float h0[9])
{
    const float4* xv = (const float4*)(x + row * 8);
    float4 p = xv[0];
    float4 q = xv[1];
    int idx = (int)p.x;
    float2 e = ((const float2*)emb)[idx];
    h0[0] = e.x; h0[1] = e.y;
    h0[2] = p.y; h0[3] = p.z; h0[4] = p.w;
    h0[5] = q.x; h0[6] = q.y; h0[7] = q.z; h0[8] = q.w;
}

// LSTM cell with pre-scaled z's: zi,zo scaled +log2e; zf scaled -log2e; zg scaled +2*log2e.
// returns h, updates c (normal domain).
__device__ __forceinline__ float cellh(float zi, float zfn, float zg2, float zo, float& c){
    float A  = __builtin_amdgcn_exp2f(zi);
    float G  = __builtin_amdgcn_exp2f(zg2);
    float icg = A * (G - 1.f) * __builtin_amdgcn_rcpf((1.f + A) * (1.f + G));   // sig(i)*tanh(g)
    float Fp = __builtin_amdgcn_exp2f(zfn);
    float fs = __builtin_amdgcn_rcpf(1.f + Fp);                                  // sig(f)
    c = fmaf(fs, c, icg);
    float O  = __builtin_amdgcn_exp2f(zo);
    float T  = __builtin_amdgcn_exp2f((2.f * LOG2E) * c);
    return O * (T - 1.f) * __builtin_amdgcn_rcpf((1.f + O) * (1.f + T));         // sig(o)*tanh(c)
}

struct KParams {
    const float *x, *emb, *W1, *b1, *g1, *be1, *W2, *b2, *g2, *be2;
    const float *w1f, *u1f, *c1f, *w1r, *u1r, *c1r;
    const float *w2f, *u2f, *c2f, *w2r, *u2r, *c2r;
    float* ws;
    float* out;
    int B;
};

// manual grid barrier: 1024 blocks, 4/CU guaranteed co-resident by launch_bounds
__device__ __forceinline__ void gridbar(int* ctr, int nb){
    __syncthreads();
    if (threadIdx.x == 0){
        __threadfence();
        atomicAdd(ctr, 1);
        while (__hip_atomic_load(ctr, __ATOMIC_ACQUIRE, __HIP_MEMORY_SCOPE_AGENT) < nb)
            __builtin_amdgcn_s_sleep(8);
    }
    __syncthreads();
}

// ============ kA: h0 moments -> (grid bar) -> BN1 -> z2 store + z2 stats ============
template<int STORE_Z2>
__global__ __launch_bounds__(256, 4) void kA(KParams p)
{
    const int tid = threadIdx.x;
    const float invB = 1.f / (float)p.B;
    const bool l0 = (tid & 63) == 0;
    float* stats = p.ws;
    const int nr = (p.B + 262143) >> 18;   // sweeps of 262144 rows

    // ---------------- P1: h0 moments ----------------
    {
        float s9[9], mt[45];
        #pragma unroll
        for (int j = 0; j < 9; ++j) s9[j] = 0.f;
        #pragma unroll
        for (int t = 0; t < 45; ++t) mt[t] = 0.f;

        for (int it = 0; it < nr; ++it){
            long row = (long)it * 262144 + (long)blockIdx.x * 256 + tid;
            if (row < p.B){
                float h0[9];
                load_h0(p.x, p.emb, row, h0);
                #pragma unroll
                for (int j = 0; j < 9; ++j){
                    s9[j] += h0[j];
                    #pragma unroll
                    for (int l = j; l < 9; ++l)
                        mt[TRI(j,l)] = fmaf(h0[j], h0[l], mt[TRI(j,l)]);
                }
            }
        }
        __shared__ float sm[54];
        if (tid < 54) sm[tid] = 0.f;
        __syncthreads();
        #pragma unroll
        for (int j = 0; j < 9; ++j){
            float v = wsum(s9[j]);
            if (l0) atomicAdd(&sm[j], v);
        }
        #pragma unroll
        for (int t = 0; t < 45; ++t){
            float v = wsum(mt[t]);
            if (l0) atomicAdd(&sm[9 + t], v);
        }
        __syncthreads();
        if (tid < 9)       atomicAdd(&stats[tid], sm[tid]);
        else if (tid < 54) atomicAdd(&stats[16 + tid - 9], sm[tid]);
    }

    gridbar((int*)(stats + WS_BAR), 1024);

    // ---------------- P2: BN1 -> z2 (store) + z2 stats ----------------
    {
        __shared__ float s_sc[18], s_sh[18];
        if (tid < 18){
            int k = tid;
            float w[9];
            #pragma unroll
            for (int j = 0; j < 9; ++j) w[j] = p.W1[k*9 + j];
            float dot9 = 0.f, q = 0.f;
            #pragma unroll
            for (int j = 0; j < 9; ++j){
                dot9 = fmaf(w[j], ld_stat(&stats[j]), dot9);
                q = fmaf(w[j]*w[j], ld_stat(&stats[16 + TRI(j,j)]), q);
                #pragma unroll
                for (int l = j+1; l < 9; ++l)
                    q = fmaf(2.f*w[j]*w[l], ld_stat(&stats[16 + TRI(j,l)]), q);
            }
            float m1  = dot9 * invB;
            float var = fmaf(-m1, m1, q * invB);
            float mu  = m1 + p.b1[k];
            float sc  = p.g1[k] * __builtin_amdgcn_rsqf(var + BN_EPS);
            s_sc[k] = sc;
            s_sh[k] = fmaf(-mu, sc, p.be1[k]);
        }
        __syncthreads();

        float as[9], aq[9];
        #pragma unroll
        for (int k = 0; k < 9; ++k){ as[k] = 0.f; aq[k] = 0.f; }

        float* z2buf = p.ws + WS_Z2;
        for (int it = 0; it < nr; ++it){
            long row = (long)it * 262144 + (long)blockIdx.x * 256 + tid;
            if (row < p.B){
                float h0[9];
                load_h0(p.x, p.emb, row, h0);
                float a1[18];
                #pragma unroll
                for (int k = 0; k < 18; ++k){
                    float s = p.b1[k];
                    #pragma unroll
                    for (int j = 0; j < 9; ++j) s = fmaf(p.W1[k*9 + j], h0[j], s);
                    a1[k] = relu_(fmaf(s_sc[k], s, s_sh[k]));
                }
                #pragma unroll
                for (int k = 0; k < 9; ++k){
                    float s = p.b2[k];
                    #pragma unroll
                    for (int j = 0; j < 18; ++j) s = fmaf(p.W2[k*18 + j], a1[j], s);
                    if (STORE_Z2) z2buf[(long)k * p.B + row] = s;
                    as[k] += s; aq[k] = fmaf(s, s, aq[k]);
                }
            }
        }
        __shared__ float sm2[18];
        if (tid < 18) sm2[tid] = 0.f;
        __syncthreads();
        #pragma unroll
        for (int k = 0; k < 9; ++k){
            float s = wsum(as[k]);
            float q = wsum(aq[k]);
            if (l0){ atomicAdd(&sm2[k], s); atomicAdd(&sm2[9 + k], q); }
        }
        __syncthreads();
        if (tid < 9)       atomicAdd(&stats[64 + tid], sm2[tid]);
        else if (tid < 18) atomicAdd(&stats[80 + tid - 9], sm2[tid]);
    }
}

// ============ kPrep: BN consts + pre-scaled LSTM weights into ws ============
__global__ void kPrep(KParams p)
{
    const int tid = threadIdx.x;
    const float invB = 1.f / (float)p.B;
    float* ws = p.ws;
    const float scl[4] = { LOG2E, -LOG2E, 2.f*LOG2E, LOG2E };  // i, f, g, o

    if (tid < 18){
        // BN1 consts (for the no-ws fallback path of kB)
        int k = tid;
        float w[9];
        #pragma unroll
        for (int j = 0; j < 9; ++j) w[j] = p.W1[k*9 + j];
        float dot9 = 0.f, q = 0.f;
        #pragma unroll
        for (int j = 0; j < 9; ++j){
            dot9 = fmaf(w[j], ld_stat(&ws[j]), dot9);
            q = fmaf(w[j]*w[j], ld_stat(&ws[16 + TRI(j,j)]), q);
            #pragma unroll
            for (int l = j+1; l < 9; ++l)
                q = fmaf(2.f*w[j]*w[l], ld_stat(&ws[16 + TRI(j,l)]), q);
        }
        float m1  = dot9 * invB;
        float var = fmaf(-m1, m1, q * invB);
        float mu  = m1 + p.b1[k];
        float sc  = p.g1[k] * __builtin_amdgcn_rsqf(var + BN_EPS);
        ws[WS_BN1S + k] = sc;
        ws[WS_BN1H + k] = fmaf(-mu, sc, p.be1[k]);
    } else if (tid >= 32 && tid < 48){
        // LSTM1 row prep: 16 rows (2 dirs x 8)
        int r = tid - 32;
        int dir = r >> 3, rr = r & 7;
        const float* W = dir ? p.w1r : p.w1f;
        const float* U = dir ? p.u1r : p.u1f;
        const float* Bb = dir ? p.c1r : p.c1f;
        float sc = scl[rr >> 1];
        float* dst = ws + WS_L1 + dir * 32;
        dst[rr]            = sc * W[rr];
        dst[8 + 2*rr]      = sc * U[2*rr];
        dst[8 + 2*rr + 1]  = sc * U[2*rr + 1];
        dst[24 + rr]       = sc * Bb[rr];
    } else if (tid >= 48 && tid < 56){
        // LSTM2 row prep: 8 rows (2 dirs x 4)
        int r = tid - 48;
        int dir = r >> 2, rr = r & 3;
        const float* W = dir ? p.w2r : p.w2f;
        const float* U = dir ? p.u2r : p.u2f;
        const float* Bb = dir ? p.c2r : p.c2f;
        float sc = scl[rr];
        float* dst = ws + WS_L2 + dir * 24;
        #pragma unroll
        for (int j = 0; j < 4; ++j) dst[4*rr + j] = sc * W[4*rr + j];
        dst[16 + rr] = sc * U[rr];
        dst[20 + rr] = sc * Bb[rr];
    } else if (tid >= 64 && tid < 73){
        // BN2 consts
        int k = tid - 64;
        float mu  = ld_stat(&ws[64 + k]) * invB;
        float var = fmaf(-mu, mu, ld_stat(&ws[80 + k]) * invB);
        float sc  = p.g2[k] * __builtin_amdgcn_rsqf(var + BN_EPS);
        ws[WS_BN2S + k] = sc;
        ws[WS_BN2H + k] = fmaf(-mu, sc, p.be2[k]);
    }
}

// ============ kB: BN2 + biLSTM x2 + output (scalar, pre-scaled weights) ============
template<int USE_WS>
__global__ __launch_bounds__(256) void kB(KParams p)
{
    const int tid = threadIdx.x;
    const float* ws = p.ws;
    const float* z2buf = ws + WS_Z2;
    const float* L1F = ws + WS_L1;          // w[8], u[16], b[8]
    const float* L1R = ws + WS_L1 + 32;
    const float* L2F = ws + WS_L2;          // W[16], U[4], b[4]
    const float* L2R = ws + WS_L2 + 24;
    const int nr = (p.B + 262143) >> 18;

    for (int it = 0; it < nr; ++it){
        long row = (long)it * 262144 + (long)blockIdx.x * 256 + tid;
        if (row >= p.B) continue;

        // ---- a2 = relu(BN2(z2)) ----
        float a2[9];
        if (USE_WS){
            #pragma unroll
            for (int k = 0; k < 9; ++k){
                float z = z2buf[(long)k * p.B + row];
                a2[k] = relu_(fmaf(ws[WS_BN2S + k], z, ws[WS_BN2H + k]));
            }
        } else {
            float h0[9];
            load_h0(p.x, p.emb, row, h0);
            float a1[18];
            #pragma unroll
            for (int k = 0; k < 18; ++k){
                float s = p.b1[k];
                #pragma unroll
                for (int j = 0; j < 9; ++j) s = fmaf(p.W1[k*9 + j], h0[j], s);
                a1[k] = relu_(fmaf(ws[WS_BN1S + k], s, ws[WS_BN1H + k]));
            }
            #pragma unroll
            for (int k = 0; k < 9; ++k){
                float s = p.b2[k];
                #pragma unroll
                for (int j = 0; j < 18; ++j) s = fmaf(p.W2[k*18 + j], a1[j], s);
                a2[k] = relu_(fmaf(ws[WS_BN2S + k], s, ws[WS_BN2H + k]));
            }
        }

        // ---- biLSTM layer 1 (scalar, both dirs) ----
        float hf0 = 0.f, hf1 = 0.f, cf0 = 0.f, cf1 = 0.f;
        float hr0 = 0.f, hr1 = 0.f, cr0 = 0.f, cr1 = 0.f;
        float u_[9][4];
        #pragma unroll
        for (int s = 0; s < 9; ++s){
            const int tf = s, tr = 8 - s;
            float xf = a2[tf], xr = a2[tr];
            // fwd
            {
                const float* W = L1F; const float* U = L1F + 8; const float* Bb = L1F + 24;
                float zi0 = fmaf(W[0], xf, fmaf(U[0],  hf0, fmaf(U[1],  hf1, Bb[0])));
                float zi1 = fmaf(W[1], xf, fmaf(U[2],  hf0, fmaf(U[3],  hf1, Bb[1])));
                float zf0 = fmaf(W[2], xf, fmaf(U[4],  hf0, fmaf(U[5],  hf1, Bb[2])));
                float zf1 = fmaf(W[3], xf, fmaf(U[6],  hf0, fmaf(U[7],  hf1, Bb[3])));
                float zg0 = fmaf(W[4], xf, fmaf(U[8],  hf0, fmaf(U[9],  hf1, Bb[4])));
                float zg1 = fmaf(W[5], xf, fmaf(U[10], hf0, fmaf(U[11], hf1, Bb[5])));
                float zo0 = fmaf(W[6], xf, fmaf(U[12], hf0, fmaf(U[13], hf1, Bb[6])));
                float zo1 = fmaf(W[7], xf, fmaf(U[14], hf0, fmaf(U[15], hf1, Bb[7])));
                hf0 = cellh(zi0, zf0, zg0, zo0, cf0);
                hf1 = cellh(zi1, zf1, zg1, zo1, cf1);
            }
            // rev
            {
                const float* W = L1R; const float* U = L1R + 8; const float* Bb = L1R + 24;
                float zi0 = fmaf(W[0], xr, fmaf(U[0],  hr0, fmaf(U[1],  hr1, Bb[0])));
                float zi1 = fmaf(W[1], xr, fmaf(U[2],  hr0, fmaf(U[3],  hr1, Bb[1])));
                float zf0 = fmaf(W[2], xr, fmaf(U[4],  hr0, fmaf(U[5],  hr1, Bb[2])));
                float zf1 = fmaf(W[3], xr, fmaf(U[6],  hr0, fmaf(U[7],  hr1, Bb[3])));
                float zg0 = fmaf(W[4], xr, fmaf(U[8],  hr0, fmaf(U[9],  hr1, Bb[4])));
                float zg1 = fmaf(W[5], xr, fmaf(U[10], hr0, fmaf(U[11], hr1, Bb[5])));
                float zo0 = fmaf(W[6], xr, fmaf(U[12], hr0, fmaf(U[13], hr1, Bb[6])));
                float zo1 = fmaf(W[7], xr, fmaf(U[14], hr0, fmaf(U[15], hr1, Bb[7])));
                hr0 = cellh(zi0, zf0, zg0, zo0, cr0);
                hr1 = cellh(zi1, zf1, zg1, zo1, cr1);
            }
            u_[tf][0] = relu_(hf0);
            u_[tf][1] = relu_(hf1);
            u_[tr][2] = relu_(hr0);
            u_[tr][3] = relu_(hr1);
        }

        // ---- biLSTM layer 2 (scalar, both dirs) ----
        float h2f = 0.f, c2f = 0.f, h2r = 0.f, c2r = 0.f;
        float of[9], orr[9];
        #pragma unroll
        for (int s = 0; s < 9; ++s){
            const int tf = s, tr = 8 - s;
            // fwd
            {
                const float* W = L2F; const float* U = L2F + 16; const float* Bb = L2F + 20;
                float zi = fmaf(W[0],  u_[tf][0], fmaf(W[1],  u_[tf][1], fmaf(W[2],  u_[tf][2], fmaf(W[3],  u_[tf][3], fmaf(U[0], h2f, Bb[0])))));
                float zf = fmaf(W[4],  u_[tf][0], fmaf(W[5],  u_[tf][1], fmaf(W[6],  u_[tf][2], fmaf(W[7],  u_[tf][3], fmaf(U[1], h2f, Bb[1])))));
                float zg = fmaf(W[8],  u_[tf][0], fmaf(W[9],  u_[tf][1], fmaf(W[10], u_[tf][2], fmaf(W[11], u_[tf][3], fmaf(U[2], h2f, Bb[2])))));
                float zo = fmaf(W[12], u_[tf][0], fmaf(W[13], u_[tf][1], fmaf(W[14], u_[tf][2], fmaf(W[15], u_[tf][3], fmaf(U[3], h2f, Bb[3])))));
                h2f = cellh(zi, zf, zg, zo, c2f);
                of[tf] = h2f;
            }
            // rev
            {
                const float* W = L2R; const float* U = L2R + 16; const float* Bb = L2R + 20;
                float zi = fmaf(W[0],  u_[tr][0], fmaf(W[1],  u_[tr][1], fmaf(W[2],  u_[tr][2], fmaf(W[3],  u_[tr][3], fmaf(U[0], h2r, Bb[0])))));
                float zf = fmaf(W[4],  u_[tr][0], fmaf(W[5],  u_[tr][1], fmaf(W[6],  u_[tr][2], fmaf(W[7],  u_[tr][3], fmaf(U[1], h2r, Bb[1])))));
                float zg = fmaf(W[8],  u_[tr][0], fmaf(W[9],  u_[tr][1], fmaf(W[10], u_[tr][2], fmaf(W[11], u_[tr][3], fmaf(U[2], h2r, Bb[2])))));
                float zo = fmaf(W[12], u_[tr][0], fmaf(W[13], u_[tr][1], fmaf(W[14], u_[tr][2], fmaf(W[15], u_[tr][3], fmaf(U[3], h2r, Bb[3])))));
                h2r = cellh(zi, zf, zg, zo, c2r);
                orr[tr] = h2r;
            }
        }

        float2* op = (float2*)(p.out + row * 18);
        #pragma unroll
        for (int t = 0; t < 9; ++t) op[t] = make_float2(of[t], orr[t]);
    }
}

extern "C" void kernel_launch(void* const* d_in, const int* in_sizes, int n_in,
                              void* d_out, int out_size, void* d_ws, size_t ws_size,
                              hipStream_t stream)
{
    KParams p;
    p.x    = (const float*)d_in[0];
    p.emb  = (const float*)d_in[1];
    p.W1   = (const float*)d_in[2];
    p.b1   = (const float*)d_in[3];
    p.g1   = (const float*)d_in[4];
    p.be1  = (const float*)d_in[5];
    p.W2   = (const float*)d_in[6];
    p.b2   = (const float*)d_in[7];
    p.g2   = (const float*)d_in[8];
    p.be2  = (const float*)d_in[9];
    p.w1f  = (const float*)d_in[10];
    p.u1f  = (const float*)d_in[11];
    p.c1f  = (const float*)d_in[12];
    p.w1r  = (const float*)d_in[13];
    p.u1r  = (const float*)d_in[14];
    p.c1r  = (const float*)d_in[15];
    p.w2f  = (const float*)d_in[16];
    p.u2f  = (const float*)d_in[17];
    p.c2f  = (const float*)d_in[18];
    p.w2r  = (const float*)d_in[19];
    p.u2r  = (const float*)d_in[20];
    p.c2r  = (const float*)d_in[21];
    p.ws   = (float*)d_ws;
    p.out  = (float*)d_out;
    p.B    = in_sizes[0] / 8;

    bool use_ws = ws_size >= (size_t)(WS_Z2 + 9 * (size_t)p.B) * sizeof(float);

    // zero stats [0..89] + barrier [120..121] (prep area >=128 is overwritten)
    hipMemsetAsync(d_ws, 0, 512, stream);

    if (use_ws) kA<1><<<1024, 256, 0, stream>>>(p);
    else        kA<0><<<1024, 256, 0, stream>>>(p);

    kPrep<<<1, 128, 0, stream>>>(p);

    if (use_ws) kB<1><<<1024, 256, 0, stream>>>(p);
    else        kB<0><<<1024, 256, 0, stream>>>(p);
}

// Round 6
// 201.372 us; speedup vs baseline: 3.2850x; 1.3165x over previous
//
#include <hip/hip_runtime.h>

#define LOG2E 1.4426950408889634f
#define BN_EPS 1e-5f

// ws float offsets
#define WS_L1    128   // per dir (stride 32): w[8], u[16], b[8]  (pre-scaled)
#define WS_L2    192   // per dir (stride 24): W[16], U[4], b[4]  (pre-scaled)
#define WS_BN2S  240   // sc2[9]
#define WS_BN2H  249   // sh2[9]
#define WS_BN1S  258   // sc1[18]
#define WS_BN1H  276   // sh1[18]
#define WS_Z2    1024  // z2 cache, col-major [9][B]

__device__ __forceinline__ float relu_(float x){ return fmaxf(x, 0.f); }

__device__ __forceinline__ float wsum(float v){
    #pragma unroll
    for (int m = 32; m >= 1; m >>= 1) v += __shfl_xor(v, m, 64);
    return v;
}

__device__ constexpr int TRI(int j, int l){ return j*9 - j*(j-1)/2 + (l - j); }

__device__ __forceinline__ float ld_stat(const float* p){
    return __hip_atomic_load(p, __ATOMIC_RELAXED, __HIP_MEMORY_SCOPE_AGENT);
}

__device__ __forceinline__ void load_h0(const float* __restrict__ x, const float* __restrict__ emb,
                                        long row, float h0[9])
{
    const float4* xv = (const float4*)(x + row * 8);
    float4 p = xv[0];
    float4 q = xv[1];
    int idx = (int)p.x;
    float2 e = ((const float2*)emb)[idx];
    h0[0] = e.x; h0[1] = e.y;
    h0[2] = p.y; h0[3] = p.z; h0[4] = p.w;
    h0[5] = q.x; h0[6] = q.y; h0[7] = q.z; h0[8] = q.w;
}

// LSTM cell with pre-scaled z's: zi,zo scaled +log2e; zf scaled -log2e; zg scaled +2*log2e.
__device__ __forceinline__ float cellh(float zi, float zfn, float zg2, float zo, float& c){
    float A  = __builtin_amdgcn_exp2f(zi);
    float G  = __builtin_amdgcn_exp2f(zg2);
    float icg = A * (G - 1.f) * __builtin_amdgcn_rcpf((1.f + A) * (1.f + G));   // sig(i)*tanh(g)
    float Fp = __builtin_amdgcn_exp2f(zfn);
    float fs = __builtin_amdgcn_rcpf(1.f + Fp);                                  // sig(f)
    c = fmaf(fs, c, icg);
    float O  = __builtin_amdgcn_exp2f(zo);
    float T  = __builtin_amdgcn_exp2f((2.f * LOG2E) * c);
    return O * (T - 1.f) * __builtin_amdgcn_rcpf((1.f + O) * (1.f + T));         // sig(o)*tanh(c)
}

struct KParams {
    const float *x, *emb, *W1, *b1, *g1, *be1, *W2, *b2, *g2, *be2;
    const float *w1f, *u1f, *c1f, *w1r, *u1r, *c1r;
    const float *w2f, *u2f, *c2f, *w2r, *u2r, *c2r;
    float* ws;
    float* out;
    int B;
};

// ============ K1: h0 moments (9 sums + 45 second moments) ============
__global__ __launch_bounds__(256) void k_moments(const float* __restrict__ x, const float* __restrict__ emb,
                                                 float* __restrict__ stats, int B)
{
    float s9[9], mt[45];
    #pragma unroll
    for (int j = 0; j < 9; ++j) s9[j] = 0.f;
    #pragma unroll
    for (int t = 0; t < 45; ++t) mt[t] = 0.f;

    long base = (long)blockIdx.x * 1024 + threadIdx.x;
    #pragma unroll
    for (int r = 0; r < 4; ++r){
        long row = base + r * 256;
        if (row < B){
            float h0[9];
            load_h0(x, emb, row, h0);
            #pragma unroll
            for (int j = 0; j < 9; ++j){
                s9[j] += h0[j];
                #pragma unroll
                for (int l = j; l < 9; ++l)
                    mt[TRI(j,l)] = fmaf(h0[j], h0[l], mt[TRI(j,l)]);
            }
        }
    }
    __shared__ float sm[54];
    if (threadIdx.x < 54) sm[threadIdx.x] = 0.f;
    __syncthreads();
    bool l0 = (threadIdx.x & 63) == 0;
    #pragma unroll
    for (int j = 0; j < 9; ++j){
        float v = wsum(s9[j]);
        if (l0) atomicAdd(&sm[j], v);
    }
    #pragma unroll
    for (int t = 0; t < 45; ++t){
        float v = wsum(mt[t]);
        if (l0) atomicAdd(&sm[9 + t], v);
    }
    __syncthreads();
    if (threadIdx.x < 9)       atomicAdd(&stats[threadIdx.x], sm[threadIdx.x]);
    else if (threadIdx.x < 54) atomicAdd(&stats[16 + threadIdx.x - 9], sm[threadIdx.x]);
}

// ============ K2: BN1 (from moments) -> z2 store + z2 stats ============
template<int STORE_Z2>
__global__ __launch_bounds__(256) void k_stats2(KParams p)
{
    const int tid = threadIdx.x;
    const float invB = 1.f / (float)p.B;
    float* stats = p.ws;

    __shared__ float s_sc[18], s_sh[18];
    if (tid < 18){
        int k = tid;
        float w[9];
        #pragma unroll
        for (int j = 0; j < 9; ++j) w[j] = p.W1[k*9 + j];
        float dot9 = 0.f, q = 0.f;
        #pragma unroll
        for (int j = 0; j < 9; ++j){
            dot9 = fmaf(w[j], ld_stat(&stats[j]), dot9);
            q = fmaf(w[j]*w[j], ld_stat(&stats[16 + TRI(j,j)]), q);
            #pragma unroll
            for (int l = j+1; l < 9; ++l)
                q = fmaf(2.f*w[j]*w[l], ld_stat(&stats[16 + TRI(j,l)]), q);
        }
        float m1  = dot9 * invB;
        float var = fmaf(-m1, m1, q * invB);
        float mu  = m1 + p.b1[k];
        float sc  = p.g1[k] * __builtin_amdgcn_rsqf(var + BN_EPS);
        s_sc[k] = sc;
        s_sh[k] = fmaf(-mu, sc, p.be1[k]);
    }
    __syncthreads();

    float sc1[18], sh1[18];
    #pragma unroll
    for (int k = 0; k < 18; ++k){ sc1[k] = s_sc[k]; sh1[k] = s_sh[k]; }

    float as[9], aq[9];
    #pragma unroll
    for (int k = 0; k < 9; ++k){ as[k] = 0.f; aq[k] = 0.f; }

    float* z2buf = p.ws + WS_Z2;
    long base = (long)blockIdx.x * 1024 + tid;
    #pragma unroll
    for (int r = 0; r < 4; ++r){
        long row = base + r * 256;
        if (row < p.B){
            float h0[9];
            load_h0(p.x, p.emb, row, h0);
            float a1[18];
            #pragma unroll
            for (int k = 0; k < 18; ++k){
                float s = p.b1[k];
                #pragma unroll
                for (int j = 0; j < 9; ++j) s = fmaf(p.W1[k*9 + j], h0[j], s);
                a1[k] = relu_(fmaf(sc1[k], s, sh1[k]));
            }
            #pragma unroll
            for (int k = 0; k < 9; ++k){
                float s = p.b2[k];
                #pragma unroll
                for (int j = 0; j < 18; ++j) s = fmaf(p.W2[k*18 + j], a1[j], s);
                if (STORE_Z2) z2buf[(long)k * p.B + row] = s;
                as[k] += s; aq[k] = fmaf(s, s, aq[k]);
            }
        }
    }
    __shared__ float sm2[18];
    if (tid < 18) sm2[tid] = 0.f;
    __syncthreads();
    bool l0 = (tid & 63) == 0;
    #pragma unroll
    for (int k = 0; k < 9; ++k){
        float s = wsum(as[k]);
        float q = wsum(aq[k]);
        if (l0){ atomicAdd(&sm2[k], s); atomicAdd(&sm2[9 + k], q); }
    }
    __syncthreads();
    if (tid < 9)       atomicAdd(&stats[64 + tid], sm2[tid]);
    else if (tid < 18) atomicAdd(&stats[80 + tid - 9], sm2[tid]);
}

// ============ kPrep: BN consts + pre-scaled LSTM weights into ws ============
__global__ void kPrep(KParams p)
{
    const int tid = threadIdx.x;
    const float invB = 1.f / (float)p.B;
    float* ws = p.ws;
    const float scl[4] = { LOG2E, -LOG2E, 2.f*LOG2E, LOG2E };  // i, f, g, o

    if (tid < 18){
        // BN1 consts (no-ws fallback path of kB)
        int k = tid;
        float w[9];
        #pragma unroll
        for (int j = 0; j < 9; ++j) w[j] = p.W1[k*9 + j];
        float dot9 = 0.f, q = 0.f;
        #pragma unroll
        for (int j = 0; j < 9; ++j){
            dot9 = fmaf(w[j], ld_stat(&ws[j]), dot9);
            q = fmaf(w[j]*w[j], ld_stat(&ws[16 + TRI(j,j)]), q);
            #pragma unroll
            for (int l = j+1; l < 9; ++l)
                q = fmaf(2.f*w[j]*w[l], ld_stat(&ws[16 + TRI(j,l)]), q);
        }
        float m1  = dot9 * invB;
        float var = fmaf(-m1, m1, q * invB);
        float mu  = m1 + p.b1[k];
        float sc  = p.g1[k] * __builtin_amdgcn_rsqf(var + BN_EPS);
        ws[WS_BN1S + k] = sc;
        ws[WS_BN1H + k] = fmaf(-mu, sc, p.be1[k]);
    } else if (tid >= 32 && tid < 48){
        int r = tid - 32;
        int dir = r >> 3, rr = r & 7;
        const float* W = dir ? p.w1r : p.w1f;
        const float* U = dir ? p.u1r : p.u1f;
        const float* Bb = dir ? p.c1r : p.c1f;
        float sc = scl[rr >> 1];
        float* dst = ws + WS_L1 + dir * 32;
        dst[rr]            = sc * W[rr];
        dst[8 + 2*rr]      = sc * U[2*rr];
        dst[8 + 2*rr + 1]  = sc * U[2*rr + 1];
        dst[24 + rr]       = sc * Bb[rr];
    } else if (tid >= 48 && tid < 56){
        int r = tid - 48;
        int dir = r >> 2, rr = r & 3;
        const float* W = dir ? p.w2r : p.w2f;
        const float* U = dir ? p.u2r : p.u2f;
        const float* Bb = dir ? p.c2r : p.c2f;
        float sc = scl[rr];
        float* dst = ws + WS_L2 + dir * 24;
        #pragma unroll
        for (int j = 0; j < 4; ++j) dst[4*rr + j] = sc * W[4*rr + j];
        dst[16 + rr] = sc * U[rr];
        dst[20 + rr] = sc * Bb[rr];
    } else if (tid >= 64 && tid < 73){
        int k = tid - 64;
        float mu  = ld_stat(&ws[64 + k]) * invB;
        float var = fmaf(-mu, mu, ld_stat(&ws[80 + k]) * invB);
        float sc  = p.g2[k] * __builtin_amdgcn_rsqf(var + BN_EPS);
        ws[WS_BN2S + k] = sc;
        ws[WS_BN2H + k] = fmaf(-mu, sc, p.be2[k]);
    }
}

// ============ kB: BN2 + biLSTM x2 + output (scalar, pre-scaled weights) ============
template<int USE_WS>
__global__ __launch_bounds__(256) void kB(KParams p)
{
    const int tid = threadIdx.x;
    const float* ws = p.ws;
    const float* z2buf = ws + WS_Z2;
    const float* L1F = ws + WS_L1;          // w[8], u[16], b[8]
    const float* L1R = ws + WS_L1 + 32;
    const float* L2F = ws + WS_L2;          // W[16], U[4], b[4]
    const float* L2R = ws + WS_L2 + 24;

    long row = (long)blockIdx.x * 256 + tid;
    if (row >= p.B) return;

    // ---- a2 = relu(BN2(z2)) ----
    float a2[9];
    if (USE_WS){
        #pragma unroll
        for (int k = 0; k < 9; ++k){
            float z = z2buf[(long)k * p.B + row];
            a2[k] = relu_(fmaf(ws[WS_BN2S + k], z, ws[WS_BN2H + k]));
        }
    } else {
        float h0[9];
        load_h0(p.x, p.emb, row, h0);
        float a1[18];
        #pragma unroll
        for (int k = 0; k < 18; ++k){
            float s = p.b1[k];
            #pragma unroll
            for (int j = 0; j < 9; ++j) s = fmaf(p.W1[k*9 + j], h0[j], s);
            a1[k] = relu_(fmaf(ws[WS_BN1S + k], s, ws[WS_BN1H + k]));
        }
        #pragma unroll
        for (int k = 0; k < 9; ++k){
            float s = p.b2[k];
            #pragma unroll
            for (int j = 0; j < 18; ++j) s = fmaf(p.W2[k*18 + j], a1[j], s);
            a2[k] = relu_(fmaf(ws[WS_BN2S + k], s, ws[WS_BN2H + k]));
        }
    }

    // ---- biLSTM layer 1 (scalar, both dirs) ----
    float hf0 = 0.f, hf1 = 0.f, cf0 = 0.f, cf1 = 0.f;
    float hr0 = 0.f, hr1 = 0.f, cr0 = 0.f, cr1 = 0.f;
    float u_[9][4];
    #pragma unroll
    for (int s = 0; s < 9; ++s){
        const int tf = s, tr = 8 - s;
        float xf = a2[tf], xr = a2[tr];
        {
            const float* W = L1F; const float* U = L1F + 8; const float* Bb = L1F + 24;
            float zi0 = fmaf(W[0], xf, fmaf(U[0],  hf0, fmaf(U[1],  hf1, Bb[0])));
            float zi1 = fmaf(W[1], xf, fmaf(U[2],  hf0, fmaf(U[3],  hf1, Bb[1])));
            float zf0 = fmaf(W[2], xf, fmaf(U[4],  hf0, fmaf(U[5],  hf1, Bb[2])));
            float zf1 = fmaf(W[3], xf, fmaf(U[6],  hf0, fmaf(U[7],  hf1, Bb[3])));
            float zg0 = fmaf(W[4], xf, fmaf(U[8],  hf0, fmaf(U[9],  hf1, Bb[4])));
            float zg1 = fmaf(W[5], xf, fmaf(U[10], hf0, fmaf(U[11], hf1, Bb[5])));
            float zo0 = fmaf(W[6], xf, fmaf(U[12], hf0, fmaf(U[13], hf1, Bb[6])));
            float zo1 = fmaf(W[7], xf, fmaf(U[14], hf0, fmaf(U[15], hf1, Bb[7])));
            hf0 = cellh(zi0, zf0, zg0, zo0, cf0);
            hf1 = cellh(zi1, zf1, zg1, zo1, cf1);
        }
        {
            const float* W = L1R; const float* U = L1R + 8; const float* Bb = L1R + 24;
            float zi0 = fmaf(W[0], xr, fmaf(U[0],  hr0, fmaf(U[1],  hr1, Bb[0])));
            float zi1 = fmaf(W[1], xr, fmaf(U[2],  hr0, fmaf(U[3],  hr1, Bb[1])));
            float zf0 = fmaf(W[2], xr, fmaf(U[4],  hr0, fmaf(U[5],  hr1, Bb[2])));
            float zf1 = fmaf(W[3], xr, fmaf(U[6],  hr0, fmaf(U[7],  hr1, Bb[3])));
            float zg0 = fmaf(W[4], xr, fmaf(U[8],  hr0, fmaf(U[9],  hr1, Bb[4])));
            float zg1 = fmaf(W[5], xr, fmaf(U[10], hr0, fmaf(U[11], hr1, Bb[5])));
            float zo0 = fmaf(W[6], xr, fmaf(U[12], hr0, fmaf(U[13], hr1, Bb[6])));
            float zo1 = fmaf(W[7], xr, fmaf(U[14], hr0, fmaf(U[15], hr1, Bb[7])));
            hr0 = cellh(zi0, zf0, zg0, zo0, cr0);
            hr1 = cellh(zi1, zf1, zg1, zo1, cr1);
        }
        u_[tf][0] = relu_(hf0);
        u_[tf][1] = relu_(hf1);
        u_[tr][2] = relu_(hr0);
        u_[tr][3] = relu_(hr1);
    }

    // ---- biLSTM layer 2 (scalar, both dirs) ----
    float h2f = 0.f, c2f = 0.f, h2r = 0.f, c2r = 0.f;
    float of[9], orr[9];
    #pragma unroll
    for (int s = 0; s < 9; ++s){
        const int tf = s, tr = 8 - s;
        {
            const float* W = L2F; const float* U = L2F + 16; const float* Bb = L2F + 20;
            float zi = fmaf(W[0],  u_[tf][0], fmaf(W[1],  u_[tf][1], fmaf(W[2],  u_[tf][2], fmaf(W[3],  u_[tf][3], fmaf(U[0], h2f, Bb[0])))));
            float zf = fmaf(W[4],  u_[tf][0], fmaf(W[5],  u_[tf][1], fmaf(W[6],  u_[tf][2], fmaf(W[7],  u_[tf][3], fmaf(U[1], h2f, Bb[1])))));
            float zg = fmaf(W[8],  u_[tf][0], fmaf(W[9],  u_[tf][1], fmaf(W[10], u_[tf][2], fmaf(W[11], u_[tf][3], fmaf(U[2], h2f, Bb[2])))));
            float zo = fmaf(W[12], u_[tf][0], fmaf(W[13], u_[tf][1], fmaf(W[14], u_[tf][2], fmaf(W[15], u_[tf][3], fmaf(U[3], h2f, Bb[3])))));
            h2f = cellh(zi, zf, zg, zo, c2f);
            of[tf] = h2f;
        }
        {
            const float* W = L2R; const float* U = L2R + 16; const float* Bb = L2R + 20;
            float zi = fmaf(W[0],  u_[tr][0], fmaf(W[1],  u_[tr][1], fmaf(W[2],  u_[tr][2], fmaf(W[3],  u_[tr][3], fmaf(U[0], h2r, Bb[0])))));
            float zf = fmaf(W[4],  u_[tr][0], fmaf(W[5],  u_[tr][1], fmaf(W[6],  u_[tr][2], fmaf(W[7],  u_[tr][3], fmaf(U[1], h2r, Bb[1])))));
            float zg = fmaf(W[8],  u_[tr][0], fmaf(W[9],  u_[tr][1], fmaf(W[10], u_[tr][2], fmaf(W[11], u_[tr][3], fmaf(U[2], h2r, Bb[2])))));
            float zo = fmaf(W[12], u_[tr][0], fmaf(W[13], u_[tr][1], fmaf(W[14], u_[tr][2], fmaf(W[15], u_[tr][3], fmaf(U[3], h2r, Bb[3])))));
            h2r = cellh(zi, zf, zg, zo, c2r);
            orr[tr] = h2r;
        }
    }

    float2* op = (float2*)(p.out + row * 18);
    #pragma unroll
    for (int t = 0; t < 9; ++t) op[t] = make_float2(of[t], orr[t]);
}

extern "C" void kernel_launch(void* const* d_in, const int* in_sizes, int n_in,
                              void* d_out, int out_size, void* d_ws, size_t ws_size,
                              hipStream_t stream)
{
    KParams p;
    p.x    = (const float*)d_in[0];
    p.emb  = (const float*)d_in[1];
    p.W1   = (const float*)d_in[2];
    p.b1   = (const float*)d_in[3];
    p.g1   = (const float*)d_in[4];
    p.be1  = (const float*)d_in[5];
    p.W2   = (const float*)d_in[6];
    p.b2   = (const float*)d_in[7];
    p.g2   = (const float*)d_in[8];
    p.be2  = (const float*)d_in[9];
    p.w1f  = (const float*)d_in[10];
    p.u1f  = (const float*)d_in[11];
    p.c1f  = (const float*)d_in[12];
    p.w1r  = (const float*)d_in[13];
    p.u1r  = (const float*)d_in[14];
    p.c1r  = (const float*)d_in[15];
    p.w2f  = (const float*)d_in[16];
    p.u2f  = (const float*)d_in[17];
    p.c2f  = (const float*)d_in[18];
    p.w2r  = (const float*)d_in[19];
    p.u2r  = (const float*)d_in[20];
    p.c2r  = (const float*)d_in[21];
    p.ws   = (float*)d_ws;
    p.out  = (float*)d_out;
    p.B    = in_sizes[0] / 8;

    bool use_ws = ws_size >= (size_t)(WS_Z2 + 9 * (size_t)p.B) * sizeof(float);

    // zero stats [0..89]
    hipMemsetAsync(d_ws, 0, 512, stream);

    int nb4 = (p.B + 1023) / 1024;   // 4 rows/thread
    int nb1 = (p.B + 255) / 256;     // 1 row/thread

    k_moments<<<nb4, 256, 0, stream>>>(p.x, p.emb, p.ws, p.B);
    if (use_ws) k_stats2<1><<<nb4, 256, 0, stream>>>(p);
    else        k_stats2<0><<<nb4, 256, 0, stream>>>(p);
    kPrep<<<1, 128, 0, stream>>>(p);
    if (use_ws) kB<1><<<nb1, 256, 0, stream>>>(p);
    else        kB<0><<<nb1, 256, 0, stream>>>(p);
}